// Round 5
// baseline (1279.516 us; speedup 1.0000x reference)
//
#include <hip/hip_runtime.h>
#include <math.h>

// ---------------------------------------------------------------------------
// OneRecTokenizer. B=64 S=512 MM=1024 HID=512 T=4 NL=4 NHEAD=8 DH=64 RQ_L=3 CB=256
// Round 5: round-4 structure (global_load_lds staging, single-barrier 2-phase
// K-loop, proj XCD swizzle) with the buggy tr_read U-path reverted to the
// round-3 xT + BT-rows path (bisect).
// bf16x2 3-pass split everywhere: A*B ~= Ah*Bh + Ah*Bl + Al*Bh (rel err ~2^-17).
// ---------------------------------------------------------------------------

typedef __attribute__((ext_vector_type(8))) short   s16x8;
typedef __attribute__((ext_vector_type(8))) __bf16  bf16x8;
typedef __attribute__((ext_vector_type(4))) float   f32x4;

__device__ __forceinline__ void split2(float v, unsigned short& hi, unsigned short& lo) {
    unsigned u = __builtin_bit_cast(unsigned, v);
    hi = (unsigned short)(u >> 16);
    float hf = __builtin_bit_cast(float, u & 0xffff0000u);
    float l = v - hf;
    unsigned ul = __builtin_bit_cast(unsigned, l);
    lo = (unsigned short)((ul + 0x7fffu + ((ul >> 16) & 1u)) >> 16);
}

__device__ __forceinline__ f32x4 mfma16(bf16x8 a, bf16x8 b, f32x4 c) {
    return __builtin_amdgcn_mfma_f32_16x16x32_bf16(a, b, c, 0, 0, 0);
}

__device__ __forceinline__ void gload16(const void* g, void* l) {
    __builtin_amdgcn_global_load_lds(
        (const __attribute__((address_space(1))) unsigned*)g,
        (__attribute__((address_space(3))) unsigned*)l, 16, 0, 0);
}

// ---------------------------------------------------------------------------
// Unified bf16x2 3-pass MFMA GEMM. BN=128. out[m,n] = sum_k A[m,k]*BT[n,k].
// AMODE 0: A split bf16 (BM=32), staged via global_load_lds (lane-linear LDS,
//          XOR swizzle applied to the GLOBAL source slot and to the LDS read).
// AMODE 1: A fp32 split on the fly (BM=128, proj; ds_write staging).
// OMODE 0: fp32 out. OMODE 1: split-bf16 out. IDX: 0 plain, 1 A-scatter,
// 2 U-scatter. Single-barrier double-buffered K-loop.
// ---------------------------------------------------------------------------
template<int BM, int FM, int FN, int WR, int WC, int AMODE, int OMODE,
         int IDX, bool GELU, bool SWZ>
__global__ __launch_bounds__(256)
void mfma_gemm(const void* __restrict__ Ah_, const void* __restrict__ Al_,
               const unsigned short* __restrict__ Bh_, const unsigned short* __restrict__ Bl_,
               const float* __restrict__ bias,
               void* __restrict__ Ch_, void* __restrict__ Cl_,
               int K, int lda, int ldb, int ldc,
               long strA, long strB, long strC)
{
    constexpr int BHALF = 8192;                         // u16 per B buffer
    constexpr int AHALF = 2 * BM * 32;                  // u16 per A buffer (hi+lo)
    __shared__ __align__(16) unsigned short sA[2 * AHALF];
    __shared__ __align__(16) unsigned short sB[2 * BHALF];

    int bx = blockIdx.x, by = blockIdx.y;
    if constexpr (SWZ) {                      // XCD-chunked remap (nb % 8 == 0)
        int nb = gridDim.x * gridDim.y;
        int h  = bx + gridDim.x * by;
        int orig = (h & 7) * (nb >> 3) + (h >> 3);
        bx = orig % gridDim.x; by = orig / gridDim.x;
    }
    const int tid = threadIdx.x, z = blockIdx.z;
    const int m0 = by * BM, n0 = bx * 128;
    const int lane = tid & 63, w = tid >> 6;
    const int wr = w / WC, wc = w % WC;

    const float* Af = nullptr;
    const unsigned short *Ah = nullptr, *Al = nullptr;
    if constexpr (AMODE == 1) {
        Af = (const float*)Ah_;
    } else {
        Ah = (const unsigned short*)Ah_ + (long)z * strA;
        Al = (const unsigned short*)Al_ + (long)z * strA;
    }
    const unsigned short* Bh = Bh_ + (long)z * strB;
    const unsigned short* Bl = Bl_ + (long)z * strB;

    // ---- staging lambdas (buf in {0,1}) ----
    auto stageB = [&](int buf, int k0) {
#pragma unroll
        for (int i = 0; i < 4; i++) {
            const int c = tid + 256 * i;
            const int p = c >> 9, cc = c & 511, r = cc >> 2, sl = cc & 3;
            const int fs = (r + (r >> 2)) & 3;
            const unsigned short* g = (p ? Bl : Bh) + (long)(n0 + r) * ldb + k0 + ((sl ^ fs)) * 8;
            unsigned short* l = sB + buf * BHALF + p * 4096 + r * 32 + sl * 8;
            gload16(g, l);
        }
    };
    auto stageA = [&](int buf, int k0) {
        if constexpr (AMODE == 0) {
            const int p = tid >> 7, c = tid & 127, r = c >> 2, sl = c & 3;
            const int fs = (r + (r >> 2)) & 3;
            const unsigned short* g = (p ? Al : Ah) + (long)(m0 + r) * lda + k0 + ((sl ^ fs)) * 8;
            unsigned short* l = sA + buf * AHALF + p * (BM * 32) + r * 32 + sl * 8;
            gload16(g, l);
        } else {
            const int r = tid >> 1, hh2 = tid & 1;
            const int fs = (r + (r >> 2)) & 3;
            const float* src = Af + (long)(m0 + r) * lda + k0 + hh2 * 16;
#pragma unroll
            for (int s2 = 0; s2 < 2; s2++) {
                const int s = 2 * hh2 + s2;
                float4 v0 = *(const float4*)(src + s2 * 8);
                float4 v1 = *(const float4*)(src + s2 * 8 + 4);
                float vv[8] = {v0.x, v0.y, v0.z, v0.w, v1.x, v1.y, v1.z, v1.w};
                union { s16x8 v; unsigned short u[8]; } hu, lu;
#pragma unroll
                for (int j = 0; j < 8; j++) split2(vv[j], hu.u[j], lu.u[j]);
                *(s16x8*)&sA[buf * AHALF + r * 32 + ((s ^ fs)) * 8] = hu.v;
                *(s16x8*)&sA[buf * AHALF + BM * 32 + r * 32 + ((s ^ fs)) * 8] = lu.v;
            }
        }
    };

    f32x4 acc[FM][FN];
#pragma unroll
    for (int i = 0; i < FM; i++)
#pragma unroll
        for (int j = 0; j < FN; j++) acc[i][j] = f32x4{0.f, 0.f, 0.f, 0.f};

    const int NT = K / 32;
    int buf = 0;
    stageB(0, 0);
    stageA(0, 0);
    __syncthreads();

    const int li = lane & 15, ks = lane >> 4;

    for (int kt = 0; kt < NT; kt++) {
        if (kt + 1 < NT) { stageB(buf ^ 1, (kt + 1) * 32); stageA(buf ^ 1, (kt + 1) * 32); }
        // ---- fragments
        bf16x8 ah[FM], al[FM], bh[FN], bl[FN];
#pragma unroll
        for (int mi = 0; mi < FM; mi++) {
            const int r = wr * (FM * 16) + mi * 16 + li;
            const int fs = (r + (r >> 2)) & 3;
            ah[mi] = __builtin_bit_cast(bf16x8, *(const s16x8*)&sA[buf * AHALF + r * 32 + ((ks ^ fs)) * 8]);
            al[mi] = __builtin_bit_cast(bf16x8, *(const s16x8*)&sA[buf * AHALF + BM * 32 + r * 32 + ((ks ^ fs)) * 8]);
        }
#pragma unroll
        for (int ni = 0; ni < FN; ni++) {
            const int r = wc * (FN * 16) + ni * 16 + li;
            const int fs = (r + (r >> 2)) & 3;
            bh[ni] = __builtin_bit_cast(bf16x8, *(const s16x8*)&sB[buf * BHALF + r * 32 + ((ks ^ fs)) * 8]);
            bl[ni] = __builtin_bit_cast(bf16x8, *(const s16x8*)&sB[buf * BHALF + 4096 + r * 32 + ((ks ^ fs)) * 8]);
        }
        // ---- 3-pass MFMA
#pragma unroll
        for (int mi = 0; mi < FM; mi++)
#pragma unroll
            for (int ni = 0; ni < FN; ni++) acc[mi][ni] = mfma16(ah[mi], bh[ni], acc[mi][ni]);
#pragma unroll
        for (int mi = 0; mi < FM; mi++)
#pragma unroll
            for (int ni = 0; ni < FN; ni++) acc[mi][ni] = mfma16(ah[mi], bl[ni], acc[mi][ni]);
#pragma unroll
        for (int mi = 0; mi < FM; mi++)
#pragma unroll
            for (int ni = 0; ni < FN; ni++) acc[mi][ni] = mfma16(al[mi], bh[ni], acc[mi][ni]);
        __syncthreads();
        buf ^= 1;
    }

    // ---- epilogue (C/D: col = lane&15, row = (lane>>4)*4 + reg)
#pragma unroll
    for (int mi = 0; mi < FM; mi++)
#pragma unroll
        for (int r4 = 0; r4 < 4; r4++) {
            const int m = m0 + wr * (FM * 16) + mi * 16 + (lane >> 4) * 4 + r4;
#pragma unroll
            for (int ni = 0; ni < FN; ni++) {
                const int n = n0 + wc * (FN * 16) + ni * 16 + (lane & 15);
                float v = acc[mi][ni][r4];
                if (bias) v += bias[n];
                if constexpr (GELU) v = 0.5f * v * (1.f + erff(v * 0.70710678118654752f));
                long id;
                if constexpr (IDX == 0)      id = (long)z * strC + (long)m * ldc + n;
                else if constexpr (IDX == 1) id = ((long)(m >> 2)) * 16384
                                                + (long)((n >> 9) * 4 + (m & 3)) * 512 + (n & 511);
                else                         id = ((long)z * 4 + (m & 3)) * 4096
                                                + (long)(m >> 2) * 512 + n;
                if constexpr (OMODE == 1) {
                    unsigned short h, l; split2(v, h, l);
                    ((unsigned short*)Ch_)[id] = h;
                    ((unsigned short*)Cl_)[id] = l;
                } else {
                    ((float*)Ch_)[id] = v;
                }
            }
        }
}

// ---------------------------------------------------------------------------
// Both-operands-fp32 split MFMA over head dim (one-time weight folding).
// ---------------------------------------------------------------------------
__global__ __launch_bounds__(256)
void w2gemm(const float* __restrict__ A_, const float* __restrict__ B_,
            float scale, unsigned short* __restrict__ Th, unsigned short* __restrict__ Tl,
            long zsA, long zsB, long S1, long S2, long SM)
{
    __shared__ __align__(16) unsigned short sA[2][128][32];
    __shared__ __align__(16) unsigned short sB[2][128][32];
    const int tid = threadIdx.x, z = blockIdx.z;
    const int m0 = blockIdx.y * 128, n0 = blockIdx.x * 128;
    const int lane = tid & 63, w = tid >> 6, wr = w >> 1, wc = w & 1;
    const float* Ab = A_ + (long)(z >> 3) * zsA + (z & 7) * 64;
    const float* Bb = B_ + (long)(z >> 3) * zsB + (z & 7) * 64;

    f32x4 acc[4][4];
#pragma unroll
    for (int i = 0; i < 4; i++)
#pragma unroll
        for (int j = 0; j < 4; j++) acc[i][j] = f32x4{0.f, 0.f, 0.f, 0.f};

    for (int k0 = 0; k0 < 64; k0 += 32) {
        __syncthreads();
#pragma unroll
        for (int op = 0; op < 2; op++) {
            const float* src0 = op ? Bb : Ab;
            auto* dst = op ? sB : sA;
#pragma unroll
            for (int i = 0; i < 2; i++) {
                const int c = tid + 256 * i;
                const int r = c >> 2, s = c & 3;
                const int fs = (r + (r >> 2)) & 3;
                const float* src = src0 + (long)((op ? n0 : m0) + r) * 512 + k0 + s * 8;
                float4 v0 = *(const float4*)src;
                float4 v1 = *(const float4*)(src + 4);
                float vv[8] = {v0.x, v0.y, v0.z, v0.w, v1.x, v1.y, v1.z, v1.w};
                union { s16x8 v; unsigned short u[8]; } hh, ll;
#pragma unroll
                for (int j = 0; j < 8; j++) split2(vv[j], hh.u[j], ll.u[j]);
                *(s16x8*)&dst[0][r][(s ^ fs) * 8] = hh.v;
                *(s16x8*)&dst[1][r][(s ^ fs) * 8] = ll.v;
            }
        }
        __syncthreads();
        const int li = lane & 15, ks = lane >> 4;
        bf16x8 ah[4], al[4], bh[4], bl[4];
#pragma unroll
        for (int mi = 0; mi < 4; mi++) {
            const int r = wr * 64 + mi * 16 + li;
            const int fs = (r + (r >> 2)) & 3;
            ah[mi] = __builtin_bit_cast(bf16x8, *(const s16x8*)&sA[0][r][(ks ^ fs) * 8]);
            al[mi] = __builtin_bit_cast(bf16x8, *(const s16x8*)&sA[1][r][(ks ^ fs) * 8]);
        }
#pragma unroll
        for (int ni = 0; ni < 4; ni++) {
            const int r = wc * 64 + ni * 16 + li;
            const int fs = (r + (r >> 2)) & 3;
            bh[ni] = __builtin_bit_cast(bf16x8, *(const s16x8*)&sB[0][r][(ks ^ fs) * 8]);
            bl[ni] = __builtin_bit_cast(bf16x8, *(const s16x8*)&sB[1][r][(ks ^ fs) * 8]);
        }
#pragma unroll
        for (int mi = 0; mi < 4; mi++)
#pragma unroll
            for (int ni = 0; ni < 4; ni++) acc[mi][ni] = mfma16(ah[mi], bh[ni], acc[mi][ni]);
#pragma unroll
        for (int mi = 0; mi < 4; mi++)
#pragma unroll
            for (int ni = 0; ni < 4; ni++) acc[mi][ni] = mfma16(ah[mi], bl[ni], acc[mi][ni]);
#pragma unroll
        for (int mi = 0; mi < 4; mi++)
#pragma unroll
            for (int ni = 0; ni < 4; ni++) acc[mi][ni] = mfma16(al[mi], bh[ni], acc[mi][ni]);
    }
#pragma unroll
    for (int mi = 0; mi < 4; mi++)
#pragma unroll
        for (int r4 = 0; r4 < 4; r4++) {
            const int m = m0 + wr * 64 + mi * 16 + (lane >> 4) * 4 + r4;
#pragma unroll
            for (int ni = 0; ni < 4; ni++) {
                const int n = n0 + wc * 64 + ni * 16 + (lane & 15);
                float v = acc[mi][ni][r4] * scale;
                unsigned short h, l; split2(v, h, l);
                long id = (long)(z >> 3) * S1 + (long)(z & 7) * S2 + (long)m * SM + n;
                Th[id] = h; Tl[id] = l;
            }
        }
}

// ---- fp32 [K][N] -> split-bf16 [N][K], z-batched ---------------------------
__global__ __launch_bounds__(256)
void prep_split_T(const float* __restrict__ in, unsigned short* __restrict__ Th,
                  unsigned short* __restrict__ Tl, int ldin, int ldo,
                  long inStride, long outStride)
{
    __shared__ float t[64][68];
    const int n0 = blockIdx.x * 64, k0 = blockIdx.y * 64;
    const int z = blockIdx.z, tid = threadIdx.x;
    const float* src = in + (long)z * inStride;
#pragma unroll
    for (int i = 0; i < 4; i++) {
        int ch = tid + 256 * i;
        int r = ch >> 4, q = ch & 15;
        float4 v = *(const float4*)(src + (long)(k0 + r) * ldin + n0 + q * 4);
        t[r][q * 4 + 0] = v.x; t[r][q * 4 + 1] = v.y;
        t[r][q * 4 + 2] = v.z; t[r][q * 4 + 3] = v.w;
    }
    __syncthreads();
#pragma unroll
    for (int i = 0; i < 4; i++) {
        int ch = tid + 256 * i;
        int rc = ch >> 4, qk = ch & 15;
        union { uint2 v; unsigned short u[4]; } oh, ol;
#pragma unroll
        for (int j = 0; j < 4; j++) split2(t[qk * 4 + j][rc], oh.u[j], ol.u[j]);
        long o = (long)z * outStride + (long)(n0 + rc) * ldo + k0 + qk * 4;
        *(uint2*)(Th + o) = oh.v;
        *(uint2*)(Tl + o) = ol.v;
    }
}

// ---- fp32 [512][512] transpose, z-batched ----------------------------------
__global__ __launch_bounds__(256)
void transpose32(const float* __restrict__ in, float* __restrict__ out, long zstr)
{
    __shared__ float t[64][65];
    const int c0 = blockIdx.x * 64, r0 = blockIdx.y * 64;
    const int z = blockIdx.z, tid = threadIdx.x;
#pragma unroll
    for (int i = 0; i < 4; i++) {
        int ch = tid + 256 * i;
        int r = ch >> 4, q = ch & 15;
        float4 v = *(const float4*)(in + (long)z * zstr + (long)(r0 + r) * 512 + c0 + q * 4);
        t[r][q * 4 + 0] = v.x; t[r][q * 4 + 1] = v.y;
        t[r][q * 4 + 2] = v.z; t[r][q * 4 + 3] = v.w;
    }
    __syncthreads();
#pragma unroll
    for (int i = 0; i < 4; i++) {
        int ch = tid + 256 * i;
        int rc = ch >> 4, qk = ch & 15;
        float4 o;
        o.x = t[qk * 4 + 0][rc]; o.y = t[qk * 4 + 1][rc];
        o.z = t[qk * 4 + 2][rc]; o.w = t[qk * 4 + 3][rc];
        *(float4*)(out + (long)z * zstr + (long)(c0 + rc) * 512 + r0 + qk * 4) = o;
    }
}

// ---- x hi/lo [b*s][c] -> xT hi/lo [b][c][s] --------------------------------
__global__ __launch_bounds__(256) void transpose_x(const unsigned short* __restrict__ xh,
                                                   const unsigned short* __restrict__ xl,
                                                   unsigned short* __restrict__ xTh,
                                                   unsigned short* __restrict__ xTl)
{
    __shared__ unsigned short th[64][72], tl[64][72];
    const int b = blockIdx.z, c0 = blockIdx.x * 64, s0 = blockIdx.y * 64;
    const int tid = threadIdx.x;
    const long ibase = ((long)b * 512 + s0) * 512 + c0;
#pragma unroll
    for (int i = 0; i < 2; i++) {
        int ch = tid + 256 * i;
        int r = ch >> 3, s = ch & 7;
        *(s16x8*)&th[r][s * 8] = *(const s16x8*)(xh + ibase + (long)r * 512 + s * 8);
        *(s16x8*)&tl[r][s * 8] = *(const s16x8*)(xl + ibase + (long)r * 512 + s * 8);
    }
    __syncthreads();
    const long obase = ((long)b * 512 + c0) * 512 + s0;
#pragma unroll
    for (int i = 0; i < 2; i++) {
        int ch = tid + 256 * i;
        int rc = ch >> 3, sc = ch & 7;
        union { s16x8 v; unsigned short u[8]; } oh, ol;
#pragma unroll
        for (int j = 0; j < 8; j++) { oh.u[j] = th[sc * 8 + j][rc]; ol.u[j] = tl[sc * 8 + j][rc]; }
        *(s16x8*)(xTh + obase + (long)rc * 512 + sc * 8) = oh.v;
        *(s16x8*)(xTl + obase + (long)rc * 512 + sc * 8) = ol.v;
    }
}

// ---- biasA[l][h*512+c] = 0.125 * sum_d bq[l,hd]*Wk[l,c,hd] -----------------
__global__ __launch_bounds__(256) void biasA_k(const float* __restrict__ bq,
                                               const float* __restrict__ Wk,
                                               float* __restrict__ biasA)
{
    const int gid = blockIdx.x * 256 + threadIdx.x;     // 16384
    const int l = gid >> 12, hc = gid & 4095, h = hc >> 9, c = hc & 511;
    const float* b = bq + l * 512 + h * 64;
    const float* w = Wk + (long)l * 262144 + (long)c * 512 + h * 64;
    float s = 0.f;
#pragma unroll 16
    for (int d = 0; d < 64; d++) s = fmaf(b[d], w[d], s);
    biasA[gid] = 0.125f * s;
}

// ---- biasO[l][o] = sum_j bv[l,j]*Wo[l,j,o] + bo[l,o] -----------------------
__global__ __launch_bounds__(256) void biasO_k(const float* __restrict__ bv,
                                               const float* __restrict__ Wo,
                                               const float* __restrict__ bo,
                                               float* __restrict__ biasO)
{
    __shared__ float sbv[512];
    const int l = blockIdx.x, tid = threadIdx.x;
    sbv[tid] = bv[l * 512 + tid];
    sbv[tid + 256] = bv[l * 512 + tid + 256];
    __syncthreads();
#pragma unroll
    for (int half = 0; half < 2; half++) {
        const int o = tid + half * 256;
        float s = bo[l * 512 + o];
        const float* w = Wo + (long)l * 262144 + o;
        for (int j = 0; j < 512; j++) s = fmaf(sbv[j], w[(long)j * 512], s);
        biasO[l * 512 + o] = s;
    }
}

// ---- row softmax (width 512) with split output -----------------------------
__global__ __launch_bounds__(256) void softmax_split(const float* __restrict__ sc,
                                                     unsigned short* __restrict__ Ph,
                                                     unsigned short* __restrict__ Pl)
{
    __shared__ float red[4];
    const int tid = threadIdx.x;
    const float* row = sc + (long)blockIdx.x * 512;
    float v0 = row[tid], v1 = row[tid + 256];
    float m = fmaxf(v0, v1);
#pragma unroll
    for (int o = 32; o > 0; o >>= 1) m = fmaxf(m, __shfl_xor(m, o));
    if ((tid & 63) == 0) red[tid >> 6] = m;
    __syncthreads();
    m = fmaxf(fmaxf(red[0], red[1]), fmaxf(red[2], red[3]));
    __syncthreads();
    float e0 = expf(v0 - m), e1 = expf(v1 - m);
    float sum = e0 + e1;
#pragma unroll
    for (int o = 32; o > 0; o >>= 1) sum += __shfl_xor(sum, o);
    if ((tid & 63) == 0) red[tid >> 6] = sum;
    __syncthreads();
    sum = red[0] + red[1] + red[2] + red[3];
    float inv = 1.f / sum;
    const long base = (long)blockIdx.x * 512;
    unsigned short h, l;
    split2(e0 * inv, h, l); Ph[base + tid] = h;       Pl[base + tid] = l;
    split2(e1 * inv, h, l); Ph[base + tid + 256] = h; Pl[base + tid + 256] = l;
}

// ---- q = LayerNorm(q + delta)*g + b; also emit split q ---------------------
__global__ __launch_bounds__(256) void add_ln(float* __restrict__ q,
                                              const float* __restrict__ d,
                                              const float* __restrict__ g,
                                              const float* __restrict__ b,
                                              unsigned short* __restrict__ qh_s,
                                              unsigned short* __restrict__ ql_s)
{
    __shared__ float red[4];
    const int tid = threadIdx.x;
    const long base = (long)blockIdx.x * 512;
    float* row = q + base;
    const float* dr = d + base;
    float v0 = row[tid] + dr[tid], v1 = row[tid + 256] + dr[tid + 256];
    float s = v0 + v1;
#pragma unroll
    for (int o = 32; o > 0; o >>= 1) s += __shfl_xor(s, o);
    if ((tid & 63) == 0) red[tid >> 6] = s;
    __syncthreads();
    float mu = (red[0] + red[1] + red[2] + red[3]) * (1.f / 512.f);
    __syncthreads();
    float c0 = v0 - mu, c1 = v1 - mu;
    float sq = c0 * c0 + c1 * c1;
#pragma unroll
    for (int o = 32; o > 0; o >>= 1) sq += __shfl_xor(sq, o);
    if ((tid & 63) == 0) red[tid >> 6] = sq;
    __syncthreads();
    float var = (red[0] + red[1] + red[2] + red[3]) * (1.f / 512.f);
    float rs = rsqrtf(var + 1e-5f);
    float o0 = c0 * rs * g[tid] + b[tid];
    float o1 = c1 * rs * g[tid + 256] + b[tid + 256];
    row[tid] = o0; row[tid + 256] = o1;
    unsigned short h, l;
    split2(o0, h, l); qh_s[base + tid] = h;       ql_s[base + tid] = l;
    split2(o1, h, l); qh_s[base + tid + 256] = h; ql_s[base + tid + 256] = l;
}

// ---- q init: broadcast query_tokens, fp32 + split --------------------------
__global__ __launch_bounds__(256) void bcast_q(const float* __restrict__ qt,
                                               float* __restrict__ q,
                                               unsigned short* __restrict__ qh_s,
                                               unsigned short* __restrict__ ql_s)
{
    const int r = blockIdx.x, tid = threadIdx.x, t = r & 3;
    const long base = (long)r * 512;
    float a = qt[t * 512 + tid], c = qt[t * 512 + 256 + tid];
    q[base + tid] = a; q[base + 256 + tid] = c;
    unsigned short h, l;
    split2(a, h, l); qh_s[base + tid] = h;       ql_s[base + tid] = l;
    split2(c, h, l); qh_s[base + tid + 256] = h; ql_s[base + tid + 256] = l;
}

__global__ __launch_bounds__(256) void cb_prep(const float* __restrict__ cb,
                                               float* __restrict__ cbT,
                                               float* __restrict__ cn)
{
    __shared__ float red[4];
    const int rowi = blockIdx.x;
    const int l = rowi >> 8, j = rowi & 255;
    const int tid = threadIdx.x;
    const float* row = cb + (long)rowi * 512;
    float v0 = row[tid], v1 = row[tid + 256];
    cbT[(long)l * 131072 + (long)tid * 256 + j]         = v0;
    cbT[(long)l * 131072 + (long)(tid + 256) * 256 + j] = v1;
    float s = v0 * v0 + v1 * v1;
#pragma unroll
    for (int o = 32; o > 0; o >>= 1) s += __shfl_xor(s, o);
    if ((tid & 63) == 0) red[tid >> 6] = s;
    __syncthreads();
    if (tid == 0) cn[rowi] = red[0] + red[1] + red[2] + red[3];
}

__global__ __launch_bounds__(256) void rq_kernel(const float* __restrict__ qf,
                                                 const float* __restrict__ cb,
                                                 const float* __restrict__ cbT,
                                                 const float* __restrict__ cn,
                                                 float* __restrict__ out)
{
    __shared__ float r[512], rec[512];
    __shared__ float rd[4]; __shared__ int ri[4];
    __shared__ int sids[3];
    const int p = blockIdx.x, tid = threadIdx.x;
    r[tid]         = qf[(long)p * 512 + tid];
    r[tid + 256]   = qf[(long)p * 512 + 256 + tid];
    rec[tid] = 0.f; rec[tid + 256] = 0.f;
    __syncthreads();
    for (int l = 0; l < 3; l++) {
        const float* ct = cbT + (long)l * 131072;
        float dot = 0.f;
#pragma unroll 8
        for (int k = 0; k < 512; k++) dot = fmaf(r[k], ct[(long)k * 256 + tid], dot);
        float d2 = cn[l * 256 + tid] - 2.f * dot;
        int idx = tid;
#pragma unroll
        for (int o = 32; o > 0; o >>= 1) {
            float od = __shfl_xor(d2, o); int oi = __shfl_xor(idx, o);
            if (od < d2 || (od == d2 && oi < idx)) { d2 = od; idx = oi; }
        }
        if ((tid & 63) == 0) { rd[tid >> 6] = d2; ri[tid >> 6] = idx; }
        __syncthreads();
        if (tid == 0) {
            float bd = rd[0]; int bb = ri[0];
            for (int w = 1; w < 4; w++)
                if (rd[w] < bd || (rd[w] == bd && ri[w] < bb)) { bd = rd[w]; bb = ri[w]; }
            sids[l] = bb;
        }
        __syncthreads();
        const float* crow = cb + ((long)l * 256 + sids[l]) * 512;
        float c0 = crow[tid], c1 = crow[tid + 256];
        r[tid] -= c0; rec[tid] += c0;
        r[tid + 256] -= c1; rec[tid + 256] += c1;
        __syncthreads();
    }
    float* orec = out + 768 + (long)p * 512;
    orec[tid] = rec[tid]; orec[tid + 256] = rec[tid + 256];
    if (tid < 3) out[p * 3 + tid] = (float)sids[tid];
}

// ---------------------------------------------------------------------------
extern "C" void kernel_launch(void* const* d_in, const int* in_sizes, int n_in,
                              void* d_out, int out_size, void* d_ws, size_t ws_size,
                              hipStream_t stream)
{
    const float* mm    = (const float*)d_in[0];
    const float* projW = (const float*)d_in[1];
    const float* projb = (const float*)d_in[2];
    const float* qt    = (const float*)d_in[3];
    const float* Wq    = (const float*)d_in[4];
    const float* bq    = (const float*)d_in[5];
    const float* Wk    = (const float*)d_in[6];
    const float* Wv    = (const float*)d_in[8];
    const float* bv    = (const float*)d_in[9];
    const float* Wo    = (const float*)d_in[10];
    const float* bo    = (const float*)d_in[11];
    const float* W1    = (const float*)d_in[12];
    const float* b1    = (const float*)d_in[13];
    const float* W2    = (const float*)d_in[14];
    const float* b2    = (const float*)d_in[15];
    const float* lng   = (const float*)d_in[16];
    const float* lnb   = (const float*)d_in[17];
    const float* cbook = (const float*)d_in[18];

    char* p = (char*)d_ws;
    auto alloc = [&](size_t bytes) { char* r = p; p += (bytes + 255) & ~(size_t)255; return r; };
    unsigned short* x_h   = (unsigned short*)alloc(16777216ull * 2);
    unsigned short* x_l   = (unsigned short*)alloc(16777216ull * 2);
    unsigned short* xT_h  = (unsigned short*)alloc(16777216ull * 2);
    unsigned short* xT_l  = (unsigned short*)alloc(16777216ull * 2);
    unsigned short* pwT_h = (unsigned short*)alloc(524288ull * 2);
    unsigned short* pwT_l = (unsigned short*)alloc(524288ull * 2);
    unsigned short* MT_h  = (unsigned short*)alloc(8388608ull * 2);
    unsigned short* MT_l  = (unsigned short*)alloc(8388608ull * 2);
    unsigned short* WVOT_h= (unsigned short*)alloc(8388608ull * 2);
    unsigned short* WVOT_l= (unsigned short*)alloc(8388608ull * 2);
    float*          WoT   = (float*)alloc(1048576ull * 4);
    unsigned short* W1T_h = (unsigned short*)alloc(4194304ull * 2);
    unsigned short* W1T_l = (unsigned short*)alloc(4194304ull * 2);
    unsigned short* W2T_h = (unsigned short*)alloc(4194304ull * 2);
    unsigned short* W2T_l = (unsigned short*)alloc(4194304ull * 2);
    unsigned short* A_h   = (unsigned short*)alloc(1048576ull * 2);
    unsigned short* A_l   = (unsigned short*)alloc(1048576ull * 2);
    unsigned short* P_h   = (unsigned short*)alloc(1048576ull * 2);
    unsigned short* P_l   = (unsigned short*)alloc(1048576ull * 2);
    unsigned short* U_h   = (unsigned short*)alloc(1048576ull * 2);
    unsigned short* U_l   = (unsigned short*)alloc(1048576ull * 2);
    unsigned short* f1_h  = (unsigned short*)alloc(524288ull * 2);
    unsigned short* f1_l  = (unsigned short*)alloc(524288ull * 2);
    unsigned short* q_h   = (unsigned short*)alloc(131072ull * 2);
    unsigned short* q_l   = (unsigned short*)alloc(131072ull * 2);
    float* sc    = (float*)alloc(1048576ull * 4);
    float* q     = (float*)alloc(131072ull * 4);
    float* tmp   = (float*)alloc(131072ull * 4);
    float* cbT   = (float*)alloc(393216ull * 4);
    float* cn    = (float*)alloc(768ull * 4);
    float* biasA = (float*)alloc(16384ull * 4);
    float* biasO = (float*)alloc(2048ull * 4);

    // ---- one-time weight prep ----
    prep_split_T<<<dim3(8, 16, 1), 256, 0, stream>>>(projW, pwT_h, pwT_l, 512, 1024, 0, 0);
    prep_split_T<<<dim3(32, 8, 4), 256, 0, stream>>>(W1, W1T_h, W1T_l, 2048, 512, 1048576, 1048576);
    prep_split_T<<<dim3(8, 32, 4), 256, 0, stream>>>(W2, W2T_h, W2T_l, 512, 2048, 1048576, 1048576);
    transpose32<<<dim3(8, 8, 4), 256, 0, stream>>>(Wo, WoT, 262144);
    w2gemm<<<dim3(4, 4, 32), 256, 0, stream>>>(Wk, Wq, 0.125f, MT_h, MT_l,
        262144, 262144, 2097152, 262144, 512);
    w2gemm<<<dim3(4, 4, 32), 256, 0, stream>>>(WoT, Wv, 1.f, WVOT_h, WVOT_l,
        262144, 262144, 2097152, 512, 4096);
    biasA_k<<<64, 256, 0, stream>>>(bq, Wk, biasA);
    biasO_k<<<4, 256, 0, stream>>>(bv, Wo, bo, biasO);
    cb_prep<<<768, 256, 0, stream>>>(cbook, cbT, cn);
    bcast_q<<<256, 256, 0, stream>>>(qt, q, q_h, q_l);

    // ---- x = mm @ projW + projb (split out), then xT ----
    mfma_gemm<128, 4, 4, 2, 2, 1, 1, 0, false, true><<<dim3(4, 256, 1), 256, 0, stream>>>(
        mm, nullptr, pwT_h, pwT_l, projb, x_h, x_l, 1024, 1024, 1024, 512, 0, 0, 0);
    transpose_x<<<dim3(8, 8, 64), 256, 0, stream>>>(x_h, x_l, xT_h, xT_l);

    for (int i = 0; i < 4; i++) {
        const unsigned short* MTh = MT_h + (long)i * 2097152;
        const unsigned short* MTl = MT_l + (long)i * 2097152;
        const unsigned short* WVh = WVOT_h + (long)i * 2097152;
        const unsigned short* WVl = WVOT_l + (long)i * 2097152;
        const unsigned short* W1h = W1T_h + (long)i * 1048576;
        const unsigned short* W1l = W1T_l + (long)i * 1048576;
        const unsigned short* W2h = W2T_h + (long)i * 1048576;
        const unsigned short* W2l = W2T_l + (long)i * 1048576;
        const float* b1i = b1 + i * 2048; const float* b2i = b2 + i * 512;
        const float* gi  = lng + i * 512; const float* bi_ = lnb + i * 512;

        // A[b][ht][c] = q @ MT + biasA   (M=256, N=4096, K=512)
        mfma_gemm<32, 2, 2, 1, 4, 0, 1, 1, false, false><<<dim3(32, 8, 1), 256, 0, stream>>>(
            q_h, q_l, MTh, MTl, biasA + i * 4096, A_h, A_l, 512, 512, 512, 0, 0, 0, 0);
        // scores[b][32][s] = A_b @ x_b^T
        mfma_gemm<32, 2, 2, 1, 4, 0, 0, 0, false, false><<<dim3(4, 1, 64), 256, 0, stream>>>(
            A_h, A_l, x_h, x_l, nullptr, sc, nullptr, 512, 512, 512, 512,
            16384, 262144, 16384);
        softmax_split<<<2048, 256, 0, stream>>>(sc, P_h, P_l);
        // U[bt][h*512+c] = P_b @ x_b   (B = xT rows)
        mfma_gemm<32, 2, 2, 1, 4, 0, 1, 2, false, false><<<dim3(4, 1, 64), 256, 0, stream>>>(
            P_h, P_l, xT_h, xT_l, nullptr, U_h, U_l, 512, 512, 512, 0,
            16384, 262144, 0);
        // attn_out = U @ WVOT + biasO   (M=256, N=512, K=4096)
        mfma_gemm<32, 2, 2, 1, 4, 0, 0, 0, false, false><<<dim3(4, 8, 1), 256, 0, stream>>>(
            U_h, U_l, WVh, WVl, biasO + i * 512, tmp, nullptr, 4096, 4096, 4096, 512, 0, 0, 0);
        add_ln<<<256, 256, 0, stream>>>(q, tmp, gi, bi_, q_h, q_l);
        // ffn1: f1 = gelu(q @ W1 + b1)
        mfma_gemm<32, 2, 2, 1, 4, 0, 1, 0, true, false><<<dim3(16, 8, 1), 256, 0, stream>>>(
            q_h, q_l, W1h, W1l, b1i, f1_h, f1_l, 512, 512, 512, 2048, 0, 0, 0);
        // ffn2: tmp = f1 @ W2 + b2
        mfma_gemm<32, 2, 2, 1, 4, 0, 0, 0, false, false><<<dim3(4, 8, 1), 256, 0, stream>>>(
            f1_h, f1_l, W2h, W2l, b2i, tmp, nullptr, 2048, 2048, 2048, 512, 0, 0, 0);
        add_ln<<<256, 256, 0, stream>>>(q, tmp, gi, bi_, q_h, q_l);
    }

    rq_kernel<<<256, 256, 0, stream>>>(q, cbook, cbT, cn, (float*)d_out);
}

// Round 6
// 1081.640 us; speedup vs baseline: 1.1829x; 1.1829x over previous
//
#include <hip/hip_runtime.h>
#include <math.h>

// ---------------------------------------------------------------------------
// OneRecTokenizer. B=64 S=512 MM=1024 HID=512 T=4 NL=4 NHEAD=8 DH=64 RQ_L=3 CB=256
// Round 6: round-5 base + (a) fused scores/softmax/U kernel (1 dispatch/layer),
// (b) split-K attn_out (8x) and ffn2 (4x) with partial-summing add_ln_sum
// (fixes 32-block latency-bound kernels), (c) unchanged proj/A-gemm/ffn1.
// bf16x2 3-pass split everywhere: A*B ~= Ah*Bh + Ah*Bl + Al*Bh (rel err ~2^-17).
// ---------------------------------------------------------------------------

typedef __attribute__((ext_vector_type(8))) short   s16x8;
typedef __attribute__((ext_vector_type(8))) __bf16  bf16x8;
typedef __attribute__((ext_vector_type(4))) float   f32x4;

__device__ __forceinline__ void split2(float v, unsigned short& hi, unsigned short& lo) {
    unsigned u = __builtin_bit_cast(unsigned, v);
    hi = (unsigned short)(u >> 16);
    float hf = __builtin_bit_cast(float, u & 0xffff0000u);
    float l = v - hf;
    unsigned ul = __builtin_bit_cast(unsigned, l);
    lo = (unsigned short)((ul + 0x7fffu + ((ul >> 16) & 1u)) >> 16);
}

__device__ __forceinline__ f32x4 mfma16(bf16x8 a, bf16x8 b, f32x4 c) {
    return __builtin_amdgcn_mfma_f32_16x16x32_bf16(a, b, c, 0, 0, 0);
}

__device__ __forceinline__ void gload16(const void* g, void* l) {
    __builtin_amdgcn_global_load_lds(
        (const __attribute__((address_space(1))) unsigned*)g,
        (__attribute__((address_space(3))) unsigned*)l, 16, 0, 0);
}

__device__ __forceinline__ bf16x8 bc16(const unsigned short* p) {
    return __builtin_bit_cast(bf16x8, *(const s16x8*)p);
}

// ---------------------------------------------------------------------------
// Unified bf16x2 3-pass MFMA GEMM (round-5, proven). BN=128.
// out[m,n] = sum_k A[m,k]*BT[n,k]. AMODE 0: A split bf16 (BM=32, gload_lds).
// AMODE 1: A fp32 split on the fly (BM=128, proj). OMODE 0 fp32 / 1 split-bf16.
// IDX 0 plain (z*strC), 1 A-scatter, 2 U-scatter. Split-K via strA/strB = k
// element offsets per z, partials at z*strC.
// ---------------------------------------------------------------------------
template<int BM, int FM, int FN, int WR, int WC, int AMODE, int OMODE,
         int IDX, bool GELU, bool SWZ>
__global__ __launch_bounds__(256)
void mfma_gemm(const void* __restrict__ Ah_, const void* __restrict__ Al_,
               const unsigned short* __restrict__ Bh_, const unsigned short* __restrict__ Bl_,
               const float* __restrict__ bias,
               void* __restrict__ Ch_, void* __restrict__ Cl_,
               int K, int lda, int ldb, int ldc,
               long strA, long strB, long strC)
{
    constexpr int BHALF = 8192;
    constexpr int AHALF = 2 * BM * 32;
    __shared__ __align__(16) unsigned short sA[2 * AHALF];
    __shared__ __align__(16) unsigned short sB[2 * BHALF];

    int bx = blockIdx.x, by = blockIdx.y;
    if constexpr (SWZ) {
        int nb = gridDim.x * gridDim.y;
        int h  = bx + gridDim.x * by;
        int orig = (h & 7) * (nb >> 3) + (h >> 3);
        bx = orig % gridDim.x; by = orig / gridDim.x;
    }
    const int tid = threadIdx.x, z = blockIdx.z;
    const int m0 = by * BM, n0 = bx * 128;
    const int lane = tid & 63, w = tid >> 6;
    const int wr = w / WC, wc = w % WC;

    const float* Af = nullptr;
    const unsigned short *Ah = nullptr, *Al = nullptr;
    if constexpr (AMODE == 1) {
        Af = (const float*)Ah_;
    } else {
        Ah = (const unsigned short*)Ah_ + (long)z * strA;
        Al = (const unsigned short*)Al_ + (long)z * strA;
    }
    const unsigned short* Bh = Bh_ + (long)z * strB;
    const unsigned short* Bl = Bl_ + (long)z * strB;

    auto stageB = [&](int buf, int k0) {
#pragma unroll
        for (int i = 0; i < 4; i++) {
            const int c = tid + 256 * i;
            const int p = c >> 9, cc = c & 511, r = cc >> 2, sl = cc & 3;
            const int fs = (r + (r >> 2)) & 3;
            const unsigned short* g = (p ? Bl : Bh) + (long)(n0 + r) * ldb + k0 + ((sl ^ fs)) * 8;
            unsigned short* l = sB + buf * BHALF + p * 4096 + r * 32 + sl * 8;
            gload16(g, l);
        }
    };
    auto stageA = [&](int buf, int k0) {
        if constexpr (AMODE == 0) {
            const int p = tid >> 7, c = tid & 127, r = c >> 2, sl = c & 3;
            const int fs = (r + (r >> 2)) & 3;
            const unsigned short* g = (p ? Al : Ah) + (long)(m0 + r) * lda + k0 + ((sl ^ fs)) * 8;
            unsigned short* l = sA + buf * AHALF + p * (BM * 32) + r * 32 + sl * 8;
            gload16(g, l);
        } else {
            const int r = tid >> 1, hh2 = tid & 1;
            const int fs = (r + (r >> 2)) & 3;
            const float* src = Af + (long)(m0 + r) * lda + k0 + hh2 * 16;
#pragma unroll
            for (int s2 = 0; s2 < 2; s2++) {
                const int s = 2 * hh2 + s2;
                float4 v0 = *(const float4*)(src + s2 * 8);
                float4 v1 = *(const float4*)(src + s2 * 8 + 4);
                float vv[8] = {v0.x, v0.y, v0.z, v0.w, v1.x, v1.y, v1.z, v1.w};
                union { s16x8 v; unsigned short u[8]; } hu, lu;
#pragma unroll
                for (int j = 0; j < 8; j++) split2(vv[j], hu.u[j], lu.u[j]);
                *(s16x8*)&sA[buf * AHALF + r * 32 + ((s ^ fs)) * 8] = hu.v;
                *(s16x8*)&sA[buf * AHALF + BM * 32 + r * 32 + ((s ^ fs)) * 8] = lu.v;
            }
        }
    };

    f32x4 acc[FM][FN];
#pragma unroll
    for (int i = 0; i < FM; i++)
#pragma unroll
        for (int j = 0; j < FN; j++) acc[i][j] = f32x4{0.f, 0.f, 0.f, 0.f};

    const int NT = K / 32;
    int buf = 0;
    stageB(0, 0);
    stageA(0, 0);
    __syncthreads();

    const int li = lane & 15, ks = lane >> 4;

    for (int kt = 0; kt < NT; kt++) {
        if (kt + 1 < NT) { stageB(buf ^ 1, (kt + 1) * 32); stageA(buf ^ 1, (kt + 1) * 32); }
        bf16x8 ah[FM], al[FM], bh[FN], bl[FN];
#pragma unroll
        for (int mi = 0; mi < FM; mi++) {
            const int r = wr * (FM * 16) + mi * 16 + li;
            const int fs = (r + (r >> 2)) & 3;
            ah[mi] = bc16(&sA[buf * AHALF + r * 32 + ((ks ^ fs)) * 8]);
            al[mi] = bc16(&sA[buf * AHALF + BM * 32 + r * 32 + ((ks ^ fs)) * 8]);
        }
#pragma unroll
        for (int ni = 0; ni < FN; ni++) {
            const int r = wc * (FN * 16) + ni * 16 + li;
            const int fs = (r + (r >> 2)) & 3;
            bh[ni] = bc16(&sB[buf * BHALF + r * 32 + ((ks ^ fs)) * 8]);
            bl[ni] = bc16(&sB[buf * BHALF + 4096 + r * 32 + ((ks ^ fs)) * 8]);
        }
#pragma unroll
        for (int mi = 0; mi < FM; mi++)
#pragma unroll
            for (int ni = 0; ni < FN; ni++) acc[mi][ni] = mfma16(ah[mi], bh[ni], acc[mi][ni]);
#pragma unroll
        for (int mi = 0; mi < FM; mi++)
#pragma unroll
            for (int ni = 0; ni < FN; ni++) acc[mi][ni] = mfma16(ah[mi], bl[ni], acc[mi][ni]);
#pragma unroll
        for (int mi = 0; mi < FM; mi++)
#pragma unroll
            for (int ni = 0; ni < FN; ni++) acc[mi][ni] = mfma16(al[mi], bh[ni], acc[mi][ni]);
        __syncthreads();
        buf ^= 1;
    }

#pragma unroll
    for (int mi = 0; mi < FM; mi++)
#pragma unroll
        for (int r4 = 0; r4 < 4; r4++) {
            const int m = m0 + wr * (FM * 16) + mi * 16 + (lane >> 4) * 4 + r4;
#pragma unroll
            for (int ni = 0; ni < FN; ni++) {
                const int n = n0 + wc * (FN * 16) + ni * 16 + (lane & 15);
                float v = acc[mi][ni][r4];
                if (bias) v += bias[n];
                if constexpr (GELU) v = 0.5f * v * (1.f + erff(v * 0.70710678118654752f));
                long id;
                if constexpr (IDX == 0)      id = (long)z * strC + (long)m * ldc + n;
                else if constexpr (IDX == 1) id = ((long)(m >> 2)) * 16384
                                                + (long)((n >> 9) * 4 + (m & 3)) * 512 + (n & 511);
                else                         id = ((long)z * 4 + (m & 3)) * 4096
                                                + (long)(m >> 2) * 512 + n;
                if constexpr (OMODE == 1) {
                    unsigned short h, l; split2(v, h, l);
                    ((unsigned short*)Ch_)[id] = h;
                    ((unsigned short*)Cl_)[id] = l;
                } else {
                    ((float*)Ch_)[id] = v;
                }
            }
        }
}

// ---------------------------------------------------------------------------
// Fused attention: scores = A_b @ x_b^T -> softmax -> U = P @ x_b.
// Grid (2, 64): blockIdx.x = 16-row half of the 32 ht-rows, blockIdx.y = b.
// Phase 1/2 both 3-pass split MFMA, BT-row staging via global_load_lds.
// P kept in LDS as split bf16 in [kt][row][32] slot-swizzled layout.
// ---------------------------------------------------------------------------
__global__ __launch_bounds__(256)
void fused_attn(const unsigned short* __restrict__ A_h, const unsigned short* __restrict__ A_l,
                const unsigned short* __restrict__ x_h, const unsigned short* __restrict__ x_l,
                const unsigned short* __restrict__ xT_h, const unsigned short* __restrict__ xT_l,
                unsigned short* __restrict__ U_h, unsigned short* __restrict__ U_l)
{
    __shared__ __align__(16) unsigned short sB[2][2][8192];    // [buf][p][256r x 32k]
    __shared__ __align__(16) unsigned short sA[2][2][512];     // [buf][p][16r x 32k]
    __shared__ __align__(16) unsigned short sP[2][16][16][32]; // [p][kt][row][32]
    __shared__ float redm[4][16], reds[4][16];

    const int tid = threadIdx.x;
    const int b = blockIdx.y, r0 = blockIdx.x * 16;
    const int lane = tid & 63, w = tid >> 6;
    const int li = lane & 15, ks = lane >> 4;
    const unsigned short* Ah = A_h + b * 16384 + r0 * 512;
    const unsigned short* Al = A_l + b * 16384 + r0 * 512;
    const unsigned short* xh = x_h + (long)b * 262144;
    const unsigned short* xl = x_l + (long)b * 262144;
    const unsigned short* xTh = xT_h + (long)b * 262144;
    const unsigned short* xTl = xT_l + (long)b * 262144;

    auto stage_B = [&](int buf, const unsigned short* sh, const unsigned short* sl2,
                       int row0, int k0) {
#pragma unroll
        for (int i = 0; i < 8; i++) {
            const int c2 = tid + 256 * i;
            const int p = c2 >> 10, cc = c2 & 1023, r = cc >> 2, sl = cc & 3;
            const int fs = (r + (r >> 2)) & 3;
            const unsigned short* g = (p ? sl2 : sh) + (long)(row0 + r) * 512 + k0 + (sl ^ fs) * 8;
            gload16(g, &sB[buf][p][r * 32 + sl * 8]);
        }
    };
    auto stage_A = [&](int buf, int k0) {
        if (tid < 128) {
            const int p = tid >> 6, c = tid & 63, r = c >> 2, sl = c & 3;
            const int fs = (r + (r >> 2)) & 3;
            const unsigned short* g = (p ? Al : Ah) + (long)r * 512 + k0 + (sl ^ fs) * 8;
            gload16(g, &sA[buf][p][r * 32 + sl * 8]);
        }
    };

    f32x4 acc[8];                                  // [half*4 + ni]
#pragma unroll
    for (int i = 0; i < 8; i++) acc[i] = f32x4{0.f, 0.f, 0.f, 0.f};

    // ---------------- phase 1: scores ----------------
    stage_B(0, xh, xl, 0, 0);
    stage_A(0, 0);
    __syncthreads();
    int buf = 0;
    const int fsa = (li + (li >> 2)) & 3;
    for (int t = 0; t < 32; t++) {
        const int half = t >> 4;
        const int nt = t + 1;
        if (nt < 32) {
            stage_B(buf ^ 1, xh, xl, (nt >> 4) * 256, (nt & 15) * 32);
            stage_A(buf ^ 1, (nt & 15) * 32);
        }
        bf16x8 ah = bc16(&sA[buf][0][li * 32 + ((ks ^ fsa)) * 8]);
        bf16x8 al = bc16(&sA[buf][1][li * 32 + ((ks ^ fsa)) * 8]);
        bf16x8 bh[4], bl[4];
#pragma unroll
        for (int ni = 0; ni < 4; ni++) {
            const int r = w * 64 + ni * 16 + li;
            const int fs = (r + (r >> 2)) & 3;
            bh[ni] = bc16(&sB[buf][0][r * 32 + ((ks ^ fs)) * 8]);
            bl[ni] = bc16(&sB[buf][1][r * 32 + ((ks ^ fs)) * 8]);
        }
#pragma unroll
        for (int ni = 0; ni < 4; ni++) acc[half * 4 + ni] = mfma16(ah, bh[ni], acc[half * 4 + ni]);
#pragma unroll
        for (int ni = 0; ni < 4; ni++) acc[half * 4 + ni] = mfma16(ah, bl[ni], acc[half * 4 + ni]);
#pragma unroll
        for (int ni = 0; ni < 4; ni++) acc[half * 4 + ni] = mfma16(al, bh[ni], acc[half * 4 + ni]);
        __syncthreads();
        buf ^= 1;
    }

    // prefetch phase-2 first tile while doing softmax
    stage_B(buf, xTh, xTl, 0, 0);

    // ---------------- softmax over s (row = ks*4+r4, col = hf*256+w*64+ni*16+li)
    float M[4], S[4];
#pragma unroll
    for (int r4 = 0; r4 < 4; r4++) {
        float m = acc[0][r4];
#pragma unroll
        for (int i = 1; i < 8; i++) m = fmaxf(m, acc[i][r4]);
#pragma unroll
        for (int o = 1; o < 16; o <<= 1) m = fmaxf(m, __shfl_xor(m, o));
        M[r4] = m;
    }
    if (li == 0) {
#pragma unroll
        for (int r4 = 0; r4 < 4; r4++) redm[w][ks * 4 + r4] = M[r4];
    }
    __syncthreads();
#pragma unroll
    for (int r4 = 0; r4 < 4; r4++)
        M[r4] = fmaxf(fmaxf(redm[0][ks * 4 + r4], redm[1][ks * 4 + r4]),
                      fmaxf(redm[2][ks * 4 + r4], redm[3][ks * 4 + r4]));
#pragma unroll
    for (int i = 0; i < 8; i++)
#pragma unroll
        for (int r4 = 0; r4 < 4; r4++) acc[i][r4] = expf(acc[i][r4] - M[r4]);
#pragma unroll
    for (int r4 = 0; r4 < 4; r4++) {
        float s = 0.f;
#pragma unroll
        for (int i = 0; i < 8; i++) s += acc[i][r4];
#pragma unroll
        for (int o = 1; o < 16; o <<= 1) s += __shfl_xor(s, o);
        S[r4] = s;
    }
    if (li == 0) {
#pragma unroll
        for (int r4 = 0; r4 < 4; r4++) reds[w][ks * 4 + r4] = S[r4];
    }
    __syncthreads();
#pragma unroll
    for (int r4 = 0; r4 < 4; r4++) {
        float s = reds[0][ks * 4 + r4] + reds[1][ks * 4 + r4]
                + reds[2][ks * 4 + r4] + reds[3][ks * 4 + r4];
        S[r4] = 1.f / s;
    }
    // write P (split) to sP[p][kt][row][ (kks^fs)*8 + j ]
#pragma unroll
    for (int i = 0; i < 8; i++) {
        const int hf = i >> 2, ni = i & 3;
        const int s = hf * 256 + w * 64 + ni * 16 + li;
        const int kt = s >> 5, kks = (s >> 3) & 3, j = s & 7;
#pragma unroll
        for (int r4 = 0; r4 < 4; r4++) {
            const int row = ks * 4 + r4;
            const int fs = (row + (row >> 2)) & 3;
            unsigned short h, l2; split2(acc[i][r4] * S[r4], h, l2);
            sP[0][kt][row][(kks ^ fs) * 8 + j] = h;
            sP[1][kt][row][(kks ^ fs) * 8 + j] = l2;
        }
    }
    __syncthreads();

    // ---------------- phase 2: U = P @ x_b (B = xT rows) ----------------
    f32x4 acc2[8];
#pragma unroll
    for (int i = 0; i < 8; i++) acc2[i] = f32x4{0.f, 0.f, 0.f, 0.f};
    for (int t = 0; t < 32; t++) {
        const int half = t >> 4, kt = t & 15;
        const int nt = t + 1;
        if (nt < 32) stage_B(buf ^ 1, xTh, xTl, (nt >> 4) * 256, (nt & 15) * 32);
        bf16x8 ph = bc16(&sP[0][kt][li][(ks ^ fsa) * 8]);
        bf16x8 pl = bc16(&sP[1][kt][li][(ks ^ fsa) * 8]);
        bf16x8 bh[4], bl[4];
#pragma unroll
        for (int ni = 0; ni < 4; ni++) {
            const int r = w * 64 + ni * 16 + li;
            const int fs = (r + (r >> 2)) & 3;
            bh[ni] = bc16(&sB[buf][0][r * 32 + ((ks ^ fs)) * 8]);
            bl[ni] = bc16(&sB[buf][1][r * 32 + ((ks ^ fs)) * 8]);
        }
#pragma unroll
        for (int ni = 0; ni < 4; ni++) acc2[half * 4 + ni] = mfma16(ph, bh[ni], acc2[half * 4 + ni]);
#pragma unroll
        for (int ni = 0; ni < 4; ni++) acc2[half * 4 + ni] = mfma16(ph, bl[ni], acc2[half * 4 + ni]);
#pragma unroll
        for (int ni = 0; ni < 4; ni++) acc2[half * 4 + ni] = mfma16(pl, bh[ni], acc2[half * 4 + ni]);
        __syncthreads();
        buf ^= 1;
    }

    // epilogue: U-scatter  U[(b*4+(m&3))*4096 + (m>>2)*512 + n]
#pragma unroll
    for (int i = 0; i < 8; i++) {
        const int hf = i >> 2, ni = i & 3;
        const int n = hf * 256 + w * 64 + ni * 16 + li;
#pragma unroll
        for (int r4 = 0; r4 < 4; r4++) {
            const int m = r0 + ks * 4 + r4;
            const long id = ((long)b * 4 + (m & 3)) * 4096 + (long)(m >> 2) * 512 + n;
            unsigned short h, l2; split2(acc2[i][r4], h, l2);
            U_h[id] = h; U_l[id] = l2;
        }
    }
}

// ---------------------------------------------------------------------------
// Both-operands-fp32 split MFMA over head dim (one-time weight folding).
// ---------------------------------------------------------------------------
__global__ __launch_bounds__(256)
void w2gemm(const float* __restrict__ A_, const float* __restrict__ B_,
            float scale, unsigned short* __restrict__ Th, unsigned short* __restrict__ Tl,
            long zsA, long zsB, long S1, long S2, long SM)
{
    __shared__ __align__(16) unsigned short sA[2][128][32];
    __shared__ __align__(16) unsigned short sB[2][128][32];
    const int tid = threadIdx.x, z = blockIdx.z;
    const int m0 = blockIdx.y * 128, n0 = blockIdx.x * 128;
    const int lane = tid & 63, w = tid >> 6, wr = w >> 1, wc = w & 1;
    const float* Ab = A_ + (long)(z >> 3) * zsA + (z & 7) * 64;
    const float* Bb = B_ + (long)(z >> 3) * zsB + (z & 7) * 64;

    f32x4 acc[4][4];
#pragma unroll
    for (int i = 0; i < 4; i++)
#pragma unroll
        for (int j = 0; j < 4; j++) acc[i][j] = f32x4{0.f, 0.f, 0.f, 0.f};

    for (int k0 = 0; k0 < 64; k0 += 32) {
        __syncthreads();
#pragma unroll
        for (int op = 0; op < 2; op++) {
            const float* src0 = op ? Bb : Ab;
            auto* dst = op ? sB : sA;
#pragma unroll
            for (int i = 0; i < 2; i++) {
                const int c = tid + 256 * i;
                const int r = c >> 2, s = c & 3;
                const int fs = (r + (r >> 2)) & 3;
                const float* src = src0 + (long)((op ? n0 : m0) + r) * 512 + k0 + s * 8;
                float4 v0 = *(const float4*)src;
                float4 v1 = *(const float4*)(src + 4);
                float vv[8] = {v0.x, v0.y, v0.z, v0.w, v1.x, v1.y, v1.z, v1.w};
                union { s16x8 v; unsigned short u[8]; } hh, ll;
#pragma unroll
                for (int j = 0; j < 8; j++) split2(vv[j], hh.u[j], ll.u[j]);
                *(s16x8*)&dst[0][r][(s ^ fs) * 8] = hh.v;
                *(s16x8*)&dst[1][r][(s ^ fs) * 8] = ll.v;
            }
        }
        __syncthreads();
        const int li = lane & 15, ks = lane >> 4;
        bf16x8 ah[4], al[4], bh[4], bl[4];
#pragma unroll
        for (int mi = 0; mi < 4; mi++) {
            const int r = wr * 64 + mi * 16 + li;
            const int fs = (r + (r >> 2)) & 3;
            ah[mi] = bc16(&sA[0][r][(ks ^ fs) * 8]);
            al[mi] = bc16(&sA[1][r][(ks ^ fs) * 8]);
        }
#pragma unroll
        for (int ni = 0; ni < 4; ni++) {
            const int r = wc * 64 + ni * 16 + li;
            const int fs = (r + (r >> 2)) & 3;
            bh[ni] = bc16(&sB[0][r][(ks ^ fs) * 8]);
            bl[ni] = bc16(&sB[1][r][(ks ^ fs) * 8]);
        }
#pragma unroll
        for (int mi = 0; mi < 4; mi++)
#pragma unroll
            for (int ni = 0; ni < 4; ni++) acc[mi][ni] = mfma16(ah[mi], bh[ni], acc[mi][ni]);
#pragma unroll
        for (int mi = 0; mi < 4; mi++)
#pragma unroll
            for (int ni = 0; ni < 4; ni++) acc[mi][ni] = mfma16(ah[mi], bl[ni], acc[mi][ni]);
#pragma unroll
        for (int mi = 0; mi < 4; mi++)
#pragma unroll
            for (int ni = 0; ni < 4; ni++) acc[mi][ni] = mfma16(al[mi], bh[ni], acc[mi][ni]);
    }
#pragma unroll
    for (int mi = 0; mi < 4; mi++)
#pragma unroll
        for (int r4 = 0; r4 < 4; r4++) {
            const int m = m0 + wr * 64 + mi * 16 + (lane >> 4) * 4 + r4;
#pragma unroll
            for (int ni = 0; ni < 4; ni++) {
                const int n = n0 + wc * 64 + ni * 16 + (lane & 15);
                float v = acc[mi][ni][r4] * scale;
                unsigned short h, l; split2(v, h, l);
                long id = (long)(z >> 3) * S1 + (long)(z & 7) * S2 + (long)m * SM + n;
                Th[id] = h; Tl[id] = l;
            }
        }
}

// ---- fp32 [K][N] -> split-bf16 [N][K], z-batched ---------------------------
__global__ __launch_bounds__(256)
void prep_split_T(const float* __restrict__ in, unsigned short* __restrict__ Th,
                  unsigned short* __restrict__ Tl, int ldin, int ldo,
                  long inStride, long outStride)
{
    __shared__ float t[64][68];
    const int n0 = blockIdx.x * 64, k0 = blockIdx.y * 64;
    const int z = blockIdx.z, tid = threadIdx.x;
    const float* src = in + (long)z * inStride;
#pragma unroll
    for (int i = 0; i < 4; i++) {
        int ch = tid + 256 * i;
        int r = ch >> 4, q = ch & 15;
        float4 v = *(const float4*)(src + (long)(k0 + r) * ldin + n0 + q * 4);
        t[r][q * 4 + 0] = v.x; t[r][q * 4 + 1] = v.y;
        t[r][q * 4 + 2] = v.z; t[r][q * 4 + 3] = v.w;
    }
    __syncthreads();
#pragma unroll
    for (int i = 0; i < 4; i++) {
        int ch = tid + 256 * i;
        int rc = ch >> 4, qk = ch & 15;
        union { uint2 v; unsigned short u[4]; } oh, ol;
#pragma unroll
        for (int j = 0; j < 4; j++) split2(t[qk * 4 + j][rc], oh.u[j], ol.u[j]);
        long o = (long)z * outStride + (long)(n0 + rc) * ldo + k0 + qk * 4;
        *(uint2*)(Th + o) = oh.v;
        *(uint2*)(Tl + o) = ol.v;
    }
}

// ---- fp32 [512][512] transpose, z-batched ----------------------------------
__global__ __launch_bounds__(256)
void transpose32(const float* __restrict__ in, float* __restrict__ out, long zstr)
{
    __shared__ float t[64][65];
    const int c0 = blockIdx.x * 64, r0 = blockIdx.y * 64;
    const int z = blockIdx.z, tid = threadIdx.x;
#pragma unroll
    for (int i = 0; i < 4; i++) {
        int ch = tid + 256 * i;
        int r = ch >> 4, q = ch & 15;
        float4 v = *(const float4*)(in + (long)z * zstr + (long)(r0 + r) * 512 + c0 + q * 4);
        t[r][q * 4 + 0] = v.x; t[r][q * 4 + 1] = v.y;
        t[r][q * 4 + 2] = v.z; t[r][q * 4 + 3] = v.w;
    }
    __syncthreads();
#pragma unroll
    for (int i = 0; i < 4; i++) {
        int ch = tid + 256 * i;
        int rc = ch >> 4, qk = ch & 15;
        float4 o;
        o.x = t[qk * 4 + 0][rc]; o.y = t[qk * 4 + 1][rc];
        o.z = t[qk * 4 + 2][rc]; o.w = t[qk * 4 + 3][rc];
        *(float4*)(out + (long)z * zstr + (long)(c0 + rc) * 512 + r0 + qk * 4) = o;
    }
}

// ---- x hi/lo [b*s][c] -> xT hi/lo [b][c][s] --------------------------------
__global__ __launch_bounds__(256) void transpose_x(const unsigned short* __restrict__ xh,
                                                   const unsigned short* __restrict__ xl,
                                                   unsigned short* __restrict__ xTh,
                                                   unsigned short* __restrict__ xTl)
{
    __shared__ unsigned short th[64][72], tl[64][72];
    const int b = blockIdx.z, c0 = blockIdx.x * 64, s0 = blockIdx.y * 64;
    const int tid = threadIdx.x;
    const long ibase = ((long)b * 512 + s0) * 512 + c0;
#pragma unroll
    for (int i = 0; i < 2; i++) {
        int ch = tid + 256 * i;
        int r = ch >> 3, s = ch & 7;
        *(s16x8*)&th[r][s * 8] = *(const s16x8*)(xh + ibase + (long)r * 512 + s * 8);
        *(s16x8*)&tl[r][s * 8] = *(const s16x8*)(xl + ibase + (long)r * 512 + s * 8);
    }
    __syncthreads();
    const long obase = ((long)b * 512 + c0) * 512 + s0;
#pragma unroll
    for (int i = 0; i < 2; i++) {
        int ch = tid + 256 * i;
        int rc = ch >> 3, sc = ch & 7;
        union { s16x8 v; unsigned short u[8]; } oh, ol;
#pragma unroll
        for (int j = 0; j < 8; j++) { oh.u[j] = th[sc * 8 + j][rc]; ol.u[j] = tl[sc * 8 + j][rc]; }
        *(s16x8*)(xTh + obase + (long)rc * 512 + sc * 8) = oh.v;
        *(s16x8*)(xTl + obase + (long)rc * 512 + sc * 8) = ol.v;
    }
}

// ---- biasA[l][h*512+c] = 0.125 * sum_d bq[l,hd]*Wk[l,c,hd] -----------------
__global__ __launch_bounds__(256) void biasA_k(const float* __restrict__ bq,
                                               const float* __restrict__ Wk,
                                               float* __restrict__ biasA)
{
    const int gid = blockIdx.x * 256 + threadIdx.x;
    const int l = gid >> 12, hc = gid & 4095, h = hc >> 9, c = hc & 511;
    const float* b = bq + l * 512 + h * 64;
    const float* w = Wk + (long)l * 262144 + (long)c * 512 + h * 64;
    float s = 0.f;
#pragma unroll 16
    for (int d = 0; d < 64; d++) s = fmaf(b[d], w[d], s);
    biasA[gid] = 0.125f * s;
}

// ---- biasO[l][o] = sum_j bv[l,j]*Wo[l,j,o] + bo[l,o] -----------------------
__global__ __launch_bounds__(256) void biasO_k(const float* __restrict__ bv,
                                               const float* __restrict__ Wo,
                                               const float* __restrict__ bo,
                                               float* __restrict__ biasO)
{
    __shared__ float sbv[512];
    const int l = blockIdx.x, tid = threadIdx.x;
    sbv[tid] = bv[l * 512 + tid];
    sbv[tid + 256] = bv[l * 512 + tid + 256];
    __syncthreads();
#pragma unroll
    for (int half = 0; half < 2; half++) {
        const int o = tid + half * 256;
        float s = bo[l * 512 + o];
        const float* w = Wo + (long)l * 262144 + o;
        for (int j = 0; j < 512; j++) s = fmaf(sbv[j], w[(long)j * 512], s);
        biasO[l * 512 + o] = s;
    }
}

// ---- q = LayerNorm(q + sum_z parts[z] + bias)*g + b; emit split q ----------
__global__ __launch_bounds__(256) void add_ln_sum(float* __restrict__ q,
                                                  const float* __restrict__ parts, int np,
                                                  const float* __restrict__ bias,
                                                  const float* __restrict__ g,
                                                  const float* __restrict__ b,
                                                  unsigned short* __restrict__ qh_s,
                                                  unsigned short* __restrict__ ql_s)
{
    __shared__ float red[4];
    const int tid = threadIdx.x;
    const long base = (long)blockIdx.x * 512;
    float* row = q + base;
    float v0 = row[tid] + bias[tid];
    float v1 = row[tid + 256] + bias[tid + 256];
    for (int z = 0; z < np; z++) {
        v0 += parts[(long)z * 131072 + base + tid];
        v1 += parts[(long)z * 131072 + base + tid + 256];
    }
    float s = v0 + v1;
#pragma unroll
    for (int o = 32; o > 0; o >>= 1) s += __shfl_xor(s, o);
    if ((tid & 63) == 0) red[tid >> 6] = s;
    __syncthreads();
    float mu = (red[0] + red[1] + red[2] + red[3]) * (1.f / 512.f);
    __syncthreads();
    float c0 = v0 - mu, c1 = v1 - mu;
    float sq = c0 * c0 + c1 * c1;
#pragma unroll
    for (int o = 32; o > 0; o >>= 1) sq += __shfl_xor(sq, o);
    if ((tid & 63) == 0) red[tid >> 6] = sq;
    __syncthreads();
    float var = (red[0] + red[1] + red[2] + red[3]) * (1.f / 512.f);
    float rs = rsqrtf(var + 1e-5f);
    float o0 = c0 * rs * g[tid] + b[tid];
    float o1 = c1 * rs * g[tid + 256] + b[tid + 256];
    row[tid] = o0; row[tid + 256] = o1;
    unsigned short h, l;
    split2(o0, h, l); qh_s[base + tid] = h;       ql_s[base + tid] = l;
    split2(o1, h, l); qh_s[base + tid + 256] = h; ql_s[base + tid + 256] = l;
}

// ---- q init: broadcast query_tokens, fp32 + split --------------------------
__global__ __launch_bounds__(256) void bcast_q(const float* __restrict__ qt,
                                               float* __restrict__ q,
                                               unsigned short* __restrict__ qh_s,
                                               unsigned short* __restrict__ ql_s)
{
    const int r = blockIdx.x, tid = threadIdx.x, t = r & 3;
    const long base = (long)r * 512;
    float a = qt[t * 512 + tid], c = qt[t * 512 + 256 + tid];
    q[base + tid] = a; q[base + 256 + tid] = c;
    unsigned short h, l;
    split2(a, h, l); qh_s[base + tid] = h;       ql_s[base + tid] = l;
    split2(c, h, l); qh_s[base + tid + 256] = h; ql_s[base + tid + 256] = l;
}

__global__ __launch_bounds__(256) void cb_prep(const float* __restrict__ cb,
                                               float* __restrict__ cbT,
                                               float* __restrict__ cn)
{
    __shared__ float red[4];
    const int rowi = blockIdx.x;
    const int l = rowi >> 8, j = rowi & 255;
    const int tid = threadIdx.x;
    const float* row = cb + (long)rowi * 512;
    float v0 = row[tid], v1 = row[tid + 256];
    cbT[(long)l * 131072 + (long)tid * 256 + j]         = v0;
    cbT[(long)l * 131072 + (long)(tid + 256) * 256 + j] = v1;
    float s = v0 * v0 + v1 * v1;
#pragma unroll
    for (int o = 32; o > 0; o >>= 1) s += __shfl_xor(s, o);
    if ((tid & 63) == 0) red[tid >> 6] = s;
    __syncthreads();
    if (tid == 0) cn[rowi] = red[0] + red[1] + red[2] + red[3];
}

__global__ __launch_bounds__(256) void rq_kernel(const float* __restrict__ qf,
                                                 const float* __restrict__ cb,
                                                 const float* __restrict__ cbT,
                                                 const float* __restrict__ cn,
                                                 float* __restrict__ out)
{
    __shared__ float r[512], rec[512];
    __shared__ float rd[4]; __shared__ int ri[4];
    __shared__ int sids[3];
    const int p = blockIdx.x, tid = threadIdx.x;
    r[tid]         = qf[(long)p * 512 + tid];
    r[tid + 256]   = qf[(long)p * 512 + 256 + tid];
    rec[tid] = 0.f; rec[tid + 256] = 0.f;
    __syncthreads();
    for (int l = 0; l < 3; l++) {
        const float* ct = cbT + (long)l * 131072;
        float dot = 0.f;
#pragma unroll 8
        for (int k = 0; k < 512; k++) dot = fmaf(r[k], ct[(long)k * 256 + tid], dot);
        float d2 = cn[l * 256 + tid] - 2.f * dot;
        int idx = tid;
#pragma unroll
        for (int o = 32; o > 0; o >>= 1) {
            float od = __shfl_xor(d2, o); int oi = __shfl_xor(idx, o);
            if (od < d2 || (od == d2 && oi < idx)) { d2 = od; idx = oi; }
        }
        if ((tid & 63) == 0) { rd[tid >> 6] = d2; ri[tid >> 6] = idx; }
        __syncthreads();
        if (tid == 0) {
            float bd = rd[0]; int bb = ri[0];
            for (int w = 1; w < 4; w++)
                if (rd[w] < bd || (rd[w] == bd && ri[w] < bb)) { bd = rd[w]; bb = ri[w]; }
            sids[l] = bb;
        }
        __syncthreads();
        const float* crow = cb + ((long)l * 256 + sids[l]) * 512;
        float c0 = crow[tid], c1 = crow[tid + 256];
        r[tid] -= c0; rec[tid] += c0;
        r[tid + 256] -= c1; rec[tid + 256] += c1;
        __syncthreads();
    }
    float* orec = out + 768 + (long)p * 512;
    orec[tid] = rec[tid]; orec[tid + 256] = rec[tid + 256];
    if (tid < 3) out[p * 3 + tid] = (float)sids[tid];
}

// ---------------------------------------------------------------------------
extern "C" void kernel_launch(void* const* d_in, const int* in_sizes, int n_in,
                              void* d_out, int out_size, void* d_ws, size_t ws_size,
                              hipStream_t stream)
{
    const float* mm    = (const float*)d_in[0];
    const float* projW = (const float*)d_in[1];
    const float* projb = (const float*)d_in[2];
    const float* qt    = (const float*)d_in[3];
    const float* Wq    = (const float*)d_in[4];
    const float* bq    = (const float*)d_in[5];
    const float* Wk    = (const float*)d_in[6];
    const float* Wv    = (const float*)d_in[8];
    const float* bv    = (const float*)d_in[9];
    const float* Wo    = (const float*)d_in[10];
    const float* bo    = (const float*)d_in[11];
    const float* W1    = (const float*)d_in[12];
    const float* b1    = (const float*)d_in[13];
    const float* W2    = (const float*)d_in[14];
    const float* b2    = (const float*)d_in[15];
    const float* lng   = (const float*)d_in[16];
    const float* lnb   = (const float*)d_in[17];
    const float* cbook = (const float*)d_in[18];

    char* p = (char*)d_ws;
    auto alloc = [&](size_t bytes) { char* r = p; p += (bytes + 255) & ~(size_t)255; return r; };
    unsigned short* x_h   = (unsigned short*)alloc(16777216ull * 2);
    unsigned short* x_l   = (unsigned short*)alloc(16777216ull * 2);
    unsigned short* xT_h  = (unsigned short*)alloc(16777216ull * 2);
    unsigned short* xT_l  = (unsigned short*)alloc(16777216ull * 2);
    unsigned short* pwT_h = (unsigned short*)alloc(524288ull * 2);
    unsigned short* pwT_l = (unsigned short*)alloc(524288ull * 2);
    unsigned short* MT_h  = (unsigned short*)alloc(8388608ull * 2);
    unsigned short* MT_l  = (unsigned short*)alloc(8388608ull * 2);
    unsigned short* WVOT_h= (unsigned short*)alloc(8388608ull * 2);
    unsigned short* WVOT_l= (unsigned short*)alloc(8388608ull * 2);
    float*          WoT   = (float*)alloc(1048576ull * 4);
    unsigned short* W1T_h = (unsigned short*)alloc(4194304ull * 2);
    unsigned short* W1T_l = (unsigned short*)alloc(4194304ull * 2);
    unsigned short* W2T_h = (unsigned short*)alloc(4194304ull * 2);
    unsigned short* W2T_l = (unsigned short*)alloc(4194304ull * 2);
    unsigned short* A_h   = (unsigned short*)alloc(1048576ull * 2);
    unsigned short* A_l   = (unsigned short*)alloc(1048576ull * 2);
    unsigned short* U_h   = (unsigned short*)alloc(1048576ull * 2);
    unsigned short* U_l   = (unsigned short*)alloc(1048576ull * 2);
    unsigned short* f1_h  = (unsigned short*)alloc(524288ull * 2);
    unsigned short* f1_l  = (unsigned short*)alloc(524288ull * 2);
    unsigned short* q_h   = (unsigned short*)alloc(131072ull * 2);
    unsigned short* q_l   = (unsigned short*)alloc(131072ull * 2);
    float* parts = (float*)alloc(8ull * 131072 * 4);
    float* q     = (float*)alloc(131072ull * 4);
    float* cbT   = (float*)alloc(393216ull * 4);
    float* cn    = (float*)alloc(768ull * 4);
    float* biasA = (float*)alloc(16384ull * 4);
    float* biasO = (float*)alloc(2048ull * 4);

    // ---- one-time weight prep ----
    prep_split_T<<<dim3(8, 16, 1), 256, 0, stream>>>(projW, pwT_h, pwT_l, 512, 1024, 0, 0);
    prep_split_T<<<dim3(32, 8, 4), 256, 0, stream>>>(W1, W1T_h, W1T_l, 2048, 512, 1048576, 1048576);
    prep_split_T<<<dim3(8, 32, 4), 256, 0, stream>>>(W2, W2T_h, W2T_l, 512, 2048, 1048576, 1048576);
    transpose32<<<dim3(8, 8, 4), 256, 0, stream>>>(Wo, WoT, 262144);
    w2gemm<<<dim3(4, 4, 32), 256, 0, stream>>>(Wk, Wq, 0.125f, MT_h, MT_l,
        262144, 262144, 2097152, 262144, 512);
    w2gemm<<<dim3(4, 4, 32), 256, 0, stream>>>(WoT, Wv, 1.f, WVOT_h, WVOT_l,
        262144, 262144, 2097152, 512, 4096);
    biasA_k<<<64, 256, 0, stream>>>(bq, Wk, biasA);
    biasO_k<<<4, 256, 0, stream>>>(bv, Wo, bo, biasO);
    cb_prep<<<768, 256, 0, stream>>>(cbook, cbT, cn);
    bcast_q<<<256, 256, 0, stream>>>(qt, q, q_h, q_l);

    // ---- x = mm @ projW + projb (split out), then xT ----
    mfma_gemm<128, 4, 4, 2, 2, 1, 1, 0, false, true><<<dim3(4, 256, 1), 256, 0, stream>>>(
        mm, nullptr, pwT_h, pwT_l, projb, x_h, x_l, 1024, 1024, 1024, 512, 0, 0, 0);
    transpose_x<<<dim3(8, 8, 64), 256, 0, stream>>>(x_h, x_l, xT_h, xT_l);

    for (int i = 0; i < 4; i++) {
        const unsigned short* MTh = MT_h + (long)i * 2097152;
        const unsigned short* MTl = MT_l + (long)i * 2097152;
        const unsigned short* WVh = WVOT_h + (long)i * 2097152;
        const unsigned short* WVl = WVOT_l + (long)i * 2097152;
        const unsigned short* W1h = W1T_h + (long)i * 1048576;
        const unsigned short* W1l = W1T_l + (long)i * 1048576;
        const unsigned short* W2h = W2T_h + (long)i * 1048576;
        const unsigned short* W2l = W2T_l + (long)i * 1048576;
        const float* b1i = b1 + i * 2048; const float* b2i = b2 + i * 512;
        const float* gi  = lng + i * 512; const float* bi_ = lnb + i * 512;

        // A[b][ht][c] = q @ MT + biasA   (M=256, N=4096, K=512)
        mfma_gemm<32, 2, 2, 1, 4, 0, 1, 1, false, false><<<dim3(32, 8, 1), 256, 0, stream>>>(
            q_h, q_l, MTh, MTl, biasA + i * 4096, A_h, A_l, 512, 512, 512, 0, 0, 0, 0);
        // fused scores -> softmax -> U
        fused_attn<<<dim3(2, 64), 256, 0, stream>>>(A_h, A_l, x_h, x_l, xT_h, xT_l, U_h, U_l);
        // attn_out partials = U @ WVOT   (split-K 8x: K=4096 -> 8*512)
        mfma_gemm<32, 2, 2, 1, 4, 0, 0, 0, false, false><<<dim3(4, 8, 8), 256, 0, stream>>>(
            U_h, U_l, WVh, WVl, nullptr, parts, nullptr, 512, 4096, 4096, 512,
            512, 512, 131072);
        add_ln_sum<<<256, 256, 0, stream>>>(q, parts, 8, biasO + i * 512, gi, bi_, q_h, q_l);
        // ffn1: f1 = gelu(q @ W1 + b1)
        mfma_gemm<32, 2, 2, 1, 4, 0, 1, 0, true, false><<<dim3(16, 8, 1), 256, 0, stream>>>(
            q_h, q_l, W1h, W1l, b1i, f1_h, f1_l, 512, 512, 512, 2048, 0, 0, 0);
        // ffn2 partials = f1 @ W2   (split-K 4x: K=2048 -> 4*512)
        mfma_gemm<32, 2, 2, 1, 4, 0, 0, 0, false, false><<<dim3(4, 8, 4), 256, 0, stream>>>(
            f1_h, f1_l, W2h, W2l, nullptr, parts, nullptr, 512, 2048, 2048, 512,
            512, 512, 131072);
        add_ln_sum<<<256, 256, 0, stream>>>(q, parts, 4, b2i, gi, bi_, q_h, q_l);
    }

    rq_kernel<<<256, 256, 0, stream>>>(q, cbook, cbT, cn, (float*)d_out);
}